// Round 1
// baseline (559.913 us; speedup 1.0000x reference)
//
#include <hip/hip_runtime.h>
#include <stdint.h>

#define N_TOK 4096
#define DIM   1024
#define NEXP  8
#define HDIM  2048
#define NSLOT 8192   // N_TOK * K

typedef __attribute__((ext_vector_type(8))) short  short8;
typedef __attribute__((ext_vector_type(4))) float  f32x4;

__device__ inline unsigned short f2bf(float f) {
  union { float f; uint32_t u; } v; v.f = f;
  uint32_t u = v.u;
  u += 0x7fffu + ((u >> 16) & 1u);   // RNE (no NaN inputs here)
  return (unsigned short)(u >> 16);
}

// async global->LDS, 16B per lane; LDS dest is wave-uniform base + lane*16
__device__ inline void gload_lds16(const void* g, void* l) {
  __builtin_amdgcn_global_load_lds(
      (const __attribute__((address_space(1))) uint32_t*)g,
      (__attribute__((address_space(3))) uint32_t*)l, 16, 0, 0);
}

// ---------------- fp32 -> bf16 bulk convert ----------------
__global__ __launch_bounds__(256) void cvt_kernel(const float* __restrict__ s,
                                                  unsigned short* __restrict__ d,
                                                  int n4) {
  int i = blockIdx.x * blockDim.x + threadIdx.x;
  int stride = gridDim.x * blockDim.x;
  for (; i < n4; i += stride) {
    float4 f = reinterpret_cast<const float4*>(s)[i];
    ushort4 o;
    o.x = f2bf(f.x); o.y = f2bf(f.y); o.z = f2bf(f.z); o.w = f2bf(f.w);
    reinterpret_cast<ushort4*>(d)[i] = o;
  }
}

// ---------------- gating: logits, softmax, top-2 ----------------
__global__ __launch_bounds__(256) void gate_kernel(const float* __restrict__ x,
                                                   const float* __restrict__ gw,
                                                   int* __restrict__ tok_e,
                                                   float* __restrict__ tok_w) {
  __shared__ float gws[NEXP * DIM];   // 32 KB
  int tid = threadIdx.x;
  for (int i = tid; i < NEXP * DIM; i += 256) gws[i] = gw[i];
  __syncthreads();
  int lane = tid & 63;
  int token = blockIdx.x * 4 + (tid >> 6);
  const float* xr = x + (size_t)token * DIM;
  float acc[NEXP];
#pragma unroll
  for (int e = 0; e < NEXP; ++e) acc[e] = 0.f;
  for (int i = 0; i < DIM / 64; ++i) {
    float xv = xr[i * 64 + lane];
#pragma unroll
    for (int e = 0; e < NEXP; ++e) acc[e] += xv * gws[e * DIM + i * 64 + lane];
  }
#pragma unroll
  for (int off = 32; off > 0; off >>= 1) {
#pragma unroll
    for (int e = 0; e < NEXP; ++e) acc[e] += __shfl_xor(acc[e], off);
  }
  if (lane == 0) {
    float m = acc[0];
#pragma unroll
    for (int e = 1; e < NEXP; ++e) m = fmaxf(m, acc[e]);
    float ex[NEXP], Z = 0.f;
#pragma unroll
    for (int e = 0; e < NEXP; ++e) { ex[e] = expf(acc[e] - m); Z += ex[e]; }
    int b0 = 0; float v0 = ex[0];
#pragma unroll
    for (int e = 1; e < NEXP; ++e) if (ex[e] > v0) { v0 = ex[e]; b0 = e; }  // first on tie
    int b1 = -1; float v1 = -1.f;
#pragma unroll
    for (int e = 0; e < NEXP; ++e) if (e != b0 && ex[e] > v1) { v1 = ex[e]; b1 = e; }
    float p0 = v0 / Z, p1 = v1 / Z;
    float s = p0 + p1 + 1e-8f;
    tok_e[token * 2 + 0] = b0; tok_e[token * 2 + 1] = b1;
    tok_w[token * 2 + 0] = p0 / s; tok_w[token * 2 + 1] = p1 / s;
  }
}

// ---------------- compaction: expert slot lists ----------------
__global__ __launch_bounds__(1024) void route_kernel(const int* __restrict__ tok_e,
                                                     const float* __restrict__ tok_w,
                                                     int* __restrict__ slot_tok,
                                                     float* __restrict__ slot_w,
                                                     int* __restrict__ cnt_g,
                                                     int* __restrict__ offs_g) {
  __shared__ int cnt[NEXP], offs[NEXP], cur[NEXP];
  int tid = threadIdx.x;
  if (tid < NEXP) cnt[tid] = 0;
  __syncthreads();
  for (int n = tid; n < N_TOK; n += 1024) {
    atomicAdd(&cnt[tok_e[2 * n]], 1);
    atomicAdd(&cnt[tok_e[2 * n + 1]], 1);
  }
  __syncthreads();
  if (tid == 0) {
    int o = 0;
    for (int e = 0; e < NEXP; ++e) { offs[e] = o; cur[e] = o; o += cnt[e]; }
    for (int e = 0; e < NEXP; ++e) { cnt_g[e] = cnt[e]; offs_g[e] = offs[e]; }
  }
  __syncthreads();
  for (int n = tid; n < N_TOK; n += 1024) {
#pragma unroll
    for (int k = 0; k < 2; ++k) {
      int e = tok_e[2 * n + k];
      int p = atomicAdd(&cur[e], 1);
      slot_tok[p] = n;
      slot_w[p] = tok_w[2 * n + k];
    }
  }
}

// ---------------- GEMM1: h=x@w1^T, g=x@w3^T, hidden=silu(h)*g ----------------
// grid = NEXP * 32 * 16 ; 128x128 tile, BK=64, 4 waves (2x2), 16x16x32 MFMA
__global__ __launch_bounds__(256) void gemm1_kernel(const unsigned short* __restrict__ xb,
                                                    const unsigned short* __restrict__ w1b,
                                                    const unsigned short* __restrict__ w3b,
                                                    const int* __restrict__ slot_tok,
                                                    const int* __restrict__ cnt_g,
                                                    const int* __restrict__ offs_g,
                                                    unsigned short* __restrict__ hidden) {
  const int ROWT = N_TOK / 128;  // 32
  const int COLT = HDIM / 128;   // 16
  int bid = blockIdx.x;
  int e  = bid / (ROWT * COLT);
  int rt = (bid / COLT) % ROWT;
  int ct = bid % COLT;
  int cnt = cnt_g[e];
  if (rt * 128 >= cnt) return;
  int rowBase = offs_g[e] + rt * 128;

  __shared__ alignas(16) unsigned short As[128 * 64];
  __shared__ alignas(16) unsigned short B1s[128 * 64];
  __shared__ alignas(16) unsigned short B3s[128 * 64];
  __shared__ int toks[128];

  int tid = threadIdx.x;
  if (tid < 128) {
    int slot = rowBase + tid; if (slot > NSLOT - 1) slot = NSLOT - 1;
    toks[tid] = slot_tok[slot];
  }
  __syncthreads();

  int wave = tid >> 6, lane = tid & 63;
  int wr = (wave >> 1) * 64, wc = (wave & 1) * 64;
  int lrow = lane >> 3, lcol = (lane & 7) * 8;

  f32x4 hacc[4][4], gacc[4][4];
#pragma unroll
  for (int m = 0; m < 4; ++m)
#pragma unroll
    for (int n = 0; n < 4; ++n) {
      hacc[m][n] = (f32x4){0.f, 0.f, 0.f, 0.f};
      gacc[m][n] = (f32x4){0.f, 0.f, 0.f, 0.f};
    }

  const size_t wbase = (size_t)e * HDIM * DIM;
  for (int kt = 0; kt < DIM / 64; ++kt) {
    int k0 = kt * 64;
#pragma unroll
    for (int i = 0; i < 4; ++i) {
      int row = i * 32 + wave * 8 + lrow;
      gload_lds16(xb + (size_t)toks[row] * DIM + k0 + lcol, &As[(i * 32 + wave * 8) * 64]);
      gload_lds16(w1b + wbase + (size_t)(ct * 128 + row) * DIM + k0 + lcol, &B1s[(i * 32 + wave * 8) * 64]);
      gload_lds16(w3b + wbase + (size_t)(ct * 128 + row) * DIM + k0 + lcol, &B3s[(i * 32 + wave * 8) * 64]);
    }
    asm volatile("s_waitcnt vmcnt(0)" ::: "memory");
    __syncthreads();
#pragma unroll
    for (int ks = 0; ks < 2; ++ks) {
      int ko = ks * 32 + (lane >> 4) * 8;
      short8 a[4], b1[4], b3[4];
#pragma unroll
      for (int m = 0; m < 4; ++m)
        a[m] = *(const short8*)&As[(wr + m * 16 + (lane & 15)) * 64 + ko];
#pragma unroll
      for (int n = 0; n < 4; ++n) {
        b1[n] = *(const short8*)&B1s[(wc + n * 16 + (lane & 15)) * 64 + ko];
        b3[n] = *(const short8*)&B3s[(wc + n * 16 + (lane & 15)) * 64 + ko];
      }
#pragma unroll
      for (int m = 0; m < 4; ++m)
#pragma unroll
        for (int n = 0; n < 4; ++n) {
          hacc[m][n] = __builtin_amdgcn_mfma_f32_16x16x32_bf16(a[m], b1[n], hacc[m][n], 0, 0, 0);
          gacc[m][n] = __builtin_amdgcn_mfma_f32_16x16x32_bf16(a[m], b3[n], gacc[m][n], 0, 0, 0);
        }
    }
    __syncthreads();
  }

  int cbase = ct * 128 + wc;
#pragma unroll
  for (int m = 0; m < 4; ++m) {
#pragma unroll
    for (int q = 0; q < 4; ++q) {
      int r = wr + m * 16 + ((lane >> 4) * 4 + q);
      if (rt * 128 + r < cnt) {
        size_t rowoff = (size_t)(rowBase + r) * HDIM + cbase;
#pragma unroll
        for (int n = 0; n < 4; ++n) {
          float h = hacc[m][n][q], g = gacc[m][n][q];
          float val = (h / (1.f + expf(-h))) * g;   // silu(h)*g
          hidden[rowoff + n * 16 + (lane & 15)] = f2bf(val);
        }
      }
    }
  }
}

// ---------------- GEMM2: eo = act @ w2^T, weighted atomic into out ----------------
__global__ __launch_bounds__(256) void gemm2_kernel(const unsigned short* __restrict__ hidden,
                                                    const unsigned short* __restrict__ w2b,
                                                    const int* __restrict__ slot_tok,
                                                    const float* __restrict__ slot_w,
                                                    const int* __restrict__ cnt_g,
                                                    const int* __restrict__ offs_g,
                                                    float* __restrict__ out) {
  const int ROWT = N_TOK / 128;  // 32
  const int COLT = DIM / 128;    // 8
  int bid = blockIdx.x;
  int e  = bid / (ROWT * COLT);
  int rt = (bid / COLT) % ROWT;
  int ct = bid % COLT;
  int cnt = cnt_g[e];
  if (rt * 128 >= cnt) return;
  int rowBase = offs_g[e] + rt * 128;

  __shared__ alignas(16) unsigned short As[128 * 64];
  __shared__ alignas(16) unsigned short Bs[128 * 64];
  __shared__ int   toks[128];
  __shared__ float wgt[128];

  int tid = threadIdx.x;
  if (tid < 128) {
    int slot = rowBase + tid; if (slot > NSLOT - 1) slot = NSLOT - 1;
    toks[tid] = slot_tok[slot];
    wgt[tid]  = slot_w[slot];
  }
  __syncthreads();

  int wave = tid >> 6, lane = tid & 63;
  int wr = (wave >> 1) * 64, wc = (wave & 1) * 64;
  int lrow = lane >> 3, lcol = (lane & 7) * 8;

  f32x4 acc[4][4];
#pragma unroll
  for (int m = 0; m < 4; ++m)
#pragma unroll
    for (int n = 0; n < 4; ++n) acc[m][n] = (f32x4){0.f, 0.f, 0.f, 0.f};

  const size_t w2base = (size_t)e * DIM * HDIM;
  for (int kt = 0; kt < HDIM / 64; ++kt) {
    int k0 = kt * 64;
#pragma unroll
    for (int i = 0; i < 4; ++i) {
      int row = i * 32 + wave * 8 + lrow;
      int rg = rowBase + row; if (rg > NSLOT - 1) rg = NSLOT - 1;
      gload_lds16(hidden + (size_t)rg * HDIM + k0 + lcol, &As[(i * 32 + wave * 8) * 64]);
      gload_lds16(w2b + w2base + (size_t)(ct * 128 + row) * HDIM + k0 + lcol, &Bs[(i * 32 + wave * 8) * 64]);
    }
    asm volatile("s_waitcnt vmcnt(0)" ::: "memory");
    __syncthreads();
#pragma unroll
    for (int ks = 0; ks < 2; ++ks) {
      int ko = ks * 32 + (lane >> 4) * 8;
      short8 a[4], b[4];
#pragma unroll
      for (int m = 0; m < 4; ++m)
        a[m] = *(const short8*)&As[(wr + m * 16 + (lane & 15)) * 64 + ko];
#pragma unroll
      for (int n = 0; n < 4; ++n)
        b[n] = *(const short8*)&Bs[(wc + n * 16 + (lane & 15)) * 64 + ko];
#pragma unroll
      for (int m = 0; m < 4; ++m)
#pragma unroll
        for (int n = 0; n < 4; ++n)
          acc[m][n] = __builtin_amdgcn_mfma_f32_16x16x32_bf16(a[m], b[n], acc[m][n], 0, 0, 0);
    }
    __syncthreads();
  }

  int cbase = ct * 128 + wc;
#pragma unroll
  for (int m = 0; m < 4; ++m) {
#pragma unroll
    for (int q = 0; q < 4; ++q) {
      int r = wr + m * 16 + ((lane >> 4) * 4 + q);
      if (rt * 128 + r < cnt) {
        float w = wgt[r];
        float* orow = out + (size_t)toks[r] * DIM + cbase;
#pragma unroll
        for (int n = 0; n < 4; ++n)
          unsafeAtomicAdd(&orow[n * 16 + (lane & 15)], acc[m][n][q] * w);
      }
    }
  }
}

extern "C" void kernel_launch(void* const* d_in, const int* in_sizes, int n_in,
                              void* d_out, int out_size, void* d_ws, size_t ws_size,
                              hipStream_t stream) {
  const float* x  = (const float*)d_in[0];
  const float* gw = (const float*)d_in[1];
  const float* w1 = (const float*)d_in[2];
  const float* w2 = (const float*)d_in[3];  // NOTE: dict order — w2 before w3
  const float* w3 = (const float*)d_in[4];
  float* out = (float*)d_out;

  uint8_t* ws = (uint8_t*)d_ws;
  size_t off = 0;
  auto alloc = [&](size_t bytes) -> void* {
    void* p = ws + off; off += (bytes + 255) & ~255ull; return p;
  };
  unsigned short* xb     = (unsigned short*)alloc((size_t)N_TOK * DIM * 2);
  unsigned short* w1b    = (unsigned short*)alloc((size_t)NEXP * HDIM * DIM * 2);
  unsigned short* w3b    = (unsigned short*)alloc((size_t)NEXP * HDIM * DIM * 2);
  unsigned short* w2b    = (unsigned short*)alloc((size_t)NEXP * DIM * HDIM * 2);
  unsigned short* hidden = (unsigned short*)alloc((size_t)NSLOT * HDIM * 2);
  int*   tok_e    = (int*)alloc(N_TOK * 2 * 4);
  float* tok_w    = (float*)alloc(N_TOK * 2 * 4);
  int*   slot_tok = (int*)alloc(NSLOT * 4);
  float* slot_w   = (float*)alloc(NSLOT * 4);
  int*   cnt_g    = (int*)alloc(NEXP * 4);
  int*   offs_g   = (int*)alloc(NEXP * 4);

  hipMemsetAsync(d_out, 0, (size_t)out_size * sizeof(float), stream);

  cvt_kernel<<<2048, 256, 0, stream>>>(x,  xb,  N_TOK * DIM / 4);
  cvt_kernel<<<2048, 256, 0, stream>>>(w1, w1b, NEXP * HDIM * DIM / 4);
  cvt_kernel<<<2048, 256, 0, stream>>>(w3, w3b, NEXP * HDIM * DIM / 4);
  cvt_kernel<<<2048, 256, 0, stream>>>(w2, w2b, NEXP * DIM * HDIM / 4);

  gate_kernel<<<N_TOK / 4, 256, 0, stream>>>(x, gw, tok_e, tok_w);
  route_kernel<<<1, 1024, 0, stream>>>(tok_e, tok_w, slot_tok, slot_w, cnt_g, offs_g);
  gemm1_kernel<<<NEXP * (N_TOK / 128) * (HDIM / 128), 256, 0, stream>>>(
      xb, w1b, w3b, slot_tok, cnt_g, offs_g, hidden);
  gemm2_kernel<<<NEXP * (N_TOK / 128) * (DIM / 128), 256, 0, stream>>>(
      hidden, w2b, slot_tok, slot_w, cnt_g, offs_g, out);
}

// Round 3
// 464.007 us; speedup vs baseline: 1.2067x; 1.2067x over previous
//
#include <hip/hip_runtime.h>
#include <stdint.h>

#define N_TOK 4096
#define DIM   1024
#define NEXP  8
#define HDIM  2048
#define NSLOT 8192   // N_TOK * K

typedef __attribute__((ext_vector_type(8))) short  short8;
typedef __attribute__((ext_vector_type(4))) float  f32x4;

__device__ inline unsigned short f2bf(float f) {
  union { float f; uint32_t u; } v; v.f = f;
  uint32_t u = v.u;
  u += 0x7fffu + ((u >> 16) & 1u);   // RNE (no NaN inputs here)
  return (unsigned short)(u >> 16);
}

// async global->LDS, 16B per lane; LDS dest is wave-uniform base + lane*16
__device__ inline void gload_lds16(const void* g, void* l) {
  __builtin_amdgcn_global_load_lds(
      (const __attribute__((address_space(1))) uint32_t*)g,
      (__attribute__((address_space(3))) uint32_t*)l, 16, 0, 0);
}

// ---------------- fp32 -> bf16 bulk convert ----------------
__global__ __launch_bounds__(256) void cvt_kernel(const float* __restrict__ s,
                                                  unsigned short* __restrict__ d,
                                                  int n4) {
  int i = blockIdx.x * blockDim.x + threadIdx.x;
  int stride = gridDim.x * blockDim.x;
  for (; i < n4; i += stride) {
    float4 f = reinterpret_cast<const float4*>(s)[i];
    ushort4 o;
    o.x = f2bf(f.x); o.y = f2bf(f.y); o.z = f2bf(f.z); o.w = f2bf(f.w);
    reinterpret_cast<ushort4*>(d)[i] = o;
  }
}

// ---------------- gating: logits, softmax, top-2 ----------------
__global__ __launch_bounds__(256) void gate_kernel(const float* __restrict__ x,
                                                   const float* __restrict__ gw,
                                                   int* __restrict__ tok_e,
                                                   float* __restrict__ tok_w) {
  __shared__ float gws[NEXP * DIM];   // 32 KB
  int tid = threadIdx.x;
  for (int i = tid; i < NEXP * DIM; i += 256) gws[i] = gw[i];
  __syncthreads();
  int lane = tid & 63;
  int token = blockIdx.x * 4 + (tid >> 6);
  const float* xr = x + (size_t)token * DIM;
  float acc[NEXP];
#pragma unroll
  for (int e = 0; e < NEXP; ++e) acc[e] = 0.f;
  for (int i = 0; i < DIM / 64; ++i) {
    float xv = xr[i * 64 + lane];
#pragma unroll
    for (int e = 0; e < NEXP; ++e) acc[e] += xv * gws[e * DIM + i * 64 + lane];
  }
#pragma unroll
  for (int off = 32; off > 0; off >>= 1) {
#pragma unroll
    for (int e = 0; e < NEXP; ++e) acc[e] += __shfl_xor(acc[e], off);
  }
  if (lane == 0) {
    float m = acc[0];
#pragma unroll
    for (int e = 1; e < NEXP; ++e) m = fmaxf(m, acc[e]);
    float ex[NEXP], Z = 0.f;
#pragma unroll
    for (int e = 0; e < NEXP; ++e) { ex[e] = expf(acc[e] - m); Z += ex[e]; }
    int b0 = 0; float v0 = ex[0];
#pragma unroll
    for (int e = 1; e < NEXP; ++e) if (ex[e] > v0) { v0 = ex[e]; b0 = e; }  // first on tie
    int b1 = -1; float v1 = -1.f;
#pragma unroll
    for (int e = 0; e < NEXP; ++e) if (e != b0 && ex[e] > v1) { v1 = ex[e]; b1 = e; }
    float p0 = v0 / Z, p1 = v1 / Z;
    float s = p0 + p1 + 1e-8f;
    tok_e[token * 2 + 0] = b0; tok_e[token * 2 + 1] = b1;
    tok_w[token * 2 + 0] = p0 / s; tok_w[token * 2 + 1] = p1 / s;
  }
}

// ---------------- compaction: expert slot lists ----------------
__global__ __launch_bounds__(1024) void route_kernel(const int* __restrict__ tok_e,
                                                     const float* __restrict__ tok_w,
                                                     int* __restrict__ slot_tok,
                                                     float* __restrict__ slot_w,
                                                     int* __restrict__ cnt_g,
                                                     int* __restrict__ offs_g) {
  __shared__ int cnt[NEXP], offs[NEXP], cur[NEXP];
  int tid = threadIdx.x;
  if (tid < NEXP) cnt[tid] = 0;
  __syncthreads();
  for (int n = tid; n < N_TOK; n += 1024) {
    atomicAdd(&cnt[tok_e[2 * n]], 1);
    atomicAdd(&cnt[tok_e[2 * n + 1]], 1);
  }
  __syncthreads();
  if (tid == 0) {
    int o = 0;
    for (int e = 0; e < NEXP; ++e) { offs[e] = o; cur[e] = o; o += cnt[e]; }
    for (int e = 0; e < NEXP; ++e) { cnt_g[e] = cnt[e]; offs_g[e] = offs[e]; }
  }
  __syncthreads();
  for (int n = tid; n < N_TOK; n += 1024) {
#pragma unroll
    for (int k = 0; k < 2; ++k) {
      int e = tok_e[2 * n + k];
      int p = atomicAdd(&cur[e], 1);
      slot_tok[p] = n;
      slot_w[p] = tok_w[2 * n + k];
    }
  }
}

// ---------------- GEMM1: h=x@w1^T, g=x@w3^T, hidden=silu(h)*g ----------------
// 256x128 tile, BK=64, 8 waves (4Mx2N, each wave 64x64 out), 2-phase dbuf, swizzled.
__global__ __launch_bounds__(512, 2) void gemm1_kernel(const unsigned short* __restrict__ xb,
                                                       const unsigned short* __restrict__ w1b,
                                                       const unsigned short* __restrict__ w3b,
                                                       const int* __restrict__ slot_tok,
                                                       const int* __restrict__ cnt_g,
                                                       const int* __restrict__ offs_g,
                                                       unsigned short* __restrict__ hidden) {
  const int ROWT = 16;            // max 4096/256 row-tiles per expert
  const int COLT = HDIM / 128;    // 16
  int bid = blockIdx.x;
  int e  = bid / (ROWT * COLT);
  int rt = (bid / COLT) % ROWT;
  int ct = bid % COLT;
  int cnt = cnt_g[e];
  if (rt * 256 >= cnt) return;
  int rowBase = offs_g[e] + rt * 256;

  __shared__ alignas(16) unsigned short As[2][256 * 64];   // 64 KB
  __shared__ alignas(16) unsigned short B1s[2][128 * 64];  // 32 KB
  __shared__ alignas(16) unsigned short B3s[2][128 * 64];  // 32 KB
  __shared__ int toks[256];

  int tid = threadIdx.x;
  if (tid < 256) {
    int slot = rowBase + tid; if (slot > NSLOT - 1) slot = NSLOT - 1;
    toks[tid] = slot_tok[slot];
  }
  __syncthreads();

  int wave = tid >> 6, lane = tid & 63;
  int wr = (wave >> 1) * 64;      // 0..192 (4 M-waves)
  int wc = (wave & 1) * 64;       // 0 or 64 (2 N-waves)
  int sub = lane >> 3;            // row within 8-row chunk
  int swcol = (((lane & 7) ^ sub) << 3);  // swizzled source column (elements)

  // hoisted per-lane stage pointers (K-invariant part)
  const size_t wbase = (size_t)e * HDIM * DIM;
  const unsigned short* aptr[4];
  const unsigned short* b1ptr[2];
  const unsigned short* b3ptr[2];
#pragma unroll
  for (int i = 0; i < 4; ++i) {
    int r = (wave + i * 8) * 8 + sub;          // 0..255
    aptr[i] = xb + (size_t)toks[r] * DIM + swcol;
  }
#pragma unroll
  for (int i = 0; i < 2; ++i) {
    int r = (wave + i * 8) * 8 + sub;          // 0..127
    b1ptr[i] = w1b + wbase + (size_t)(ct * 128 + r) * DIM + swcol;
    b3ptr[i] = w3b + wbase + (size_t)(ct * 128 + r) * DIM + swcol;
  }

  f32x4 hacc[4][4], gacc[4][4];
#pragma unroll
  for (int m = 0; m < 4; ++m)
#pragma unroll
    for (int n = 0; n < 4; ++n) {
      hacc[m][n] = (f32x4){0.f, 0.f, 0.f, 0.f};
      gacc[m][n] = (f32x4){0.f, 0.f, 0.f, 0.f};
    }

  auto stage = [&](int b, int kt) {
    int k0 = kt * 64;
#pragma unroll
    for (int i = 0; i < 4; ++i)
      gload_lds16(aptr[i] + k0, &As[b][(wave + i * 8) * 512]);
#pragma unroll
    for (int i = 0; i < 2; ++i) {
      gload_lds16(b1ptr[i] + k0, &B1s[b][(wave + i * 8) * 512]);
      gload_lds16(b3ptr[i] + k0, &B3s[b][(wave + i * 8) * 512]);
    }
  };

  const int NKT = DIM / 64;   // 16
  stage(0, 0);
  asm volatile("s_waitcnt vmcnt(0)" ::: "memory");
  __syncthreads();

  int key = (lane & 7) << 3;
  for (int kt = 0; kt < NKT; ++kt) {
    int cur = kt & 1;
    if (kt + 1 < NKT) stage(cur ^ 1, kt + 1);   // prefetch next tile
#pragma unroll
    for (int ks = 0; ks < 2; ++ks) {
      int kg = ks * 32 + (lane >> 4) * 8;       // logical column
      int pc = kg ^ key;                        // physical (swizzled) column
      short8 a[4], b1v[4], b3v[4];
#pragma unroll
      for (int m = 0; m < 4; ++m)
        a[m] = *(const short8*)&As[cur][(wr + m * 16 + (lane & 15)) * 64 + pc];
#pragma unroll
      for (int n = 0; n < 4; ++n) {
        b1v[n] = *(const short8*)&B1s[cur][(wc + n * 16 + (lane & 15)) * 64 + pc];
        b3v[n] = *(const short8*)&B3s[cur][(wc + n * 16 + (lane & 15)) * 64 + pc];
      }
#pragma unroll
      for (int m = 0; m < 4; ++m)
#pragma unroll
        for (int n = 0; n < 4; ++n) {
          hacc[m][n] = __builtin_amdgcn_mfma_f32_16x16x32_bf16(a[m], b1v[n], hacc[m][n], 0, 0, 0);
          gacc[m][n] = __builtin_amdgcn_mfma_f32_16x16x32_bf16(a[m], b3v[n], gacc[m][n], 0, 0, 0);
        }
    }
    asm volatile("s_waitcnt vmcnt(0)" ::: "memory");
    __syncthreads();
  }

  int cbase = ct * 128 + wc;
#pragma unroll
  for (int m = 0; m < 4; ++m) {
#pragma unroll
    for (int q = 0; q < 4; ++q) {
      int r = wr + m * 16 + ((lane >> 4) * 4 + q);
      if (rt * 256 + r < cnt) {
        size_t rowoff = (size_t)(rowBase + r) * HDIM + cbase;
#pragma unroll
        for (int n = 0; n < 4; ++n) {
          float h = hacc[m][n][q], g = gacc[m][n][q];
          float val = (h / (1.f + expf(-h))) * g;   // silu(h)*g
          hidden[rowoff + n * 16 + (lane & 15)] = f2bf(val);
        }
      }
    }
  }
}

// ---------------- GEMM2: eo = act @ w2^T, weighted atomic into out ----------------
// 128x128 tile, BK=64, 4 waves (2x2), 2-phase dbuf LDS, swizzled reads.
__global__ __launch_bounds__(256, 2) void gemm2_kernel(const unsigned short* __restrict__ hidden,
                                                       const unsigned short* __restrict__ w2b,
                                                       const int* __restrict__ slot_tok,
                                                       const float* __restrict__ slot_w,
                                                       const int* __restrict__ cnt_g,
                                                       const int* __restrict__ offs_g,
                                                       float* __restrict__ out) {
  const int ROWT = 32;            // max 4096/128 row-tiles per expert
  const int COLT = DIM / 128;     // 8
  int bid = blockIdx.x;
  int e  = bid / (ROWT * COLT);
  int rt = (bid / COLT) % ROWT;
  int ct = bid % COLT;
  int cnt = cnt_g[e];
  if (rt * 128 >= cnt) return;
  int rowBase = offs_g[e] + rt * 128;

  __shared__ alignas(16) unsigned short As[2][128 * 64];   // 32 KB
  __shared__ alignas(16) unsigned short Bs[2][128 * 64];   // 32 KB
  __shared__ int   toks[128];
  __shared__ float wgt[128];

  int tid = threadIdx.x;
  if (tid < 128) {
    int slot = rowBase + tid; if (slot > NSLOT - 1) slot = NSLOT - 1;
    toks[tid] = slot_tok[slot];
    wgt[tid]  = slot_w[slot];
  }
  __syncthreads();

  int wave = tid >> 6, lane = tid & 63;
  int wr = (wave >> 1) * 64, wc = (wave & 1) * 64;
  int sub = lane >> 3;
  int swcol = (((lane & 7) ^ sub) << 3);

  const size_t w2base = (size_t)e * DIM * HDIM;
  const unsigned short* aptr[4];
  const unsigned short* bptr[4];
#pragma unroll
  for (int i = 0; i < 4; ++i) {
    int r = (wave + i * 4) * 8 + sub;            // 0..127
    int rg = rowBase + r; if (rg > NSLOT - 1) rg = NSLOT - 1;
    aptr[i] = hidden + (size_t)rg * HDIM + swcol;
    bptr[i] = w2b + w2base + (size_t)(ct * 128 + r) * HDIM + swcol;
  }

  f32x4 acc[4][4];
#pragma unroll
  for (int m = 0; m < 4; ++m)
#pragma unroll
    for (int n = 0; n < 4; ++n) acc[m][n] = (f32x4){0.f, 0.f, 0.f, 0.f};

  auto stage = [&](int b, int kt) {
    int k0 = kt * 64;
#pragma unroll
    for (int i = 0; i < 4; ++i) {
      gload_lds16(aptr[i] + k0, &As[b][(wave + i * 4) * 512]);
      gload_lds16(bptr[i] + k0, &Bs[b][(wave + i * 4) * 512]);
    }
  };

  const int NKT = HDIM / 64;   // 32
  stage(0, 0);
  asm volatile("s_waitcnt vmcnt(0)" ::: "memory");
  __syncthreads();

  int key = (lane & 7) << 3;
  for (int kt = 0; kt < NKT; ++kt) {
    int cur = kt & 1;
    if (kt + 1 < NKT) stage(cur ^ 1, kt + 1);
#pragma unroll
    for (int ks = 0; ks < 2; ++ks) {
      int kg = ks * 32 + (lane >> 4) * 8;
      int pc = kg ^ key;
      short8 a[4], b[4];
#pragma unroll
      for (int m = 0; m < 4; ++m)
        a[m] = *(const short8*)&As[cur][(wr + m * 16 + (lane & 15)) * 64 + pc];
#pragma unroll
      for (int n = 0; n < 4; ++n)
        b[n] = *(const short8*)&Bs[cur][(wc + n * 16 + (lane & 15)) * 64 + pc];
#pragma unroll
      for (int m = 0; m < 4; ++m)
#pragma unroll
        for (int n = 0; n < 4; ++n)
          acc[m][n] = __builtin_amdgcn_mfma_f32_16x16x32_bf16(a[m], b[n], acc[m][n], 0, 0, 0);
    }
    asm volatile("s_waitcnt vmcnt(0)" ::: "memory");
    __syncthreads();
  }

  int cbase = ct * 128 + wc;
#pragma unroll
  for (int m = 0; m < 4; ++m) {
#pragma unroll
    for (int q = 0; q < 4; ++q) {
      int r = wr + m * 16 + ((lane >> 4) * 4 + q);
      if (rt * 128 + r < cnt) {
        float w = wgt[r];
        float* orow = out + (size_t)toks[r] * DIM + cbase;
#pragma unroll
        for (int n = 0; n < 4; ++n)
          unsafeAtomicAdd(&orow[n * 16 + (lane & 15)], acc[m][n][q] * w);
      }
    }
  }
}

extern "C" void kernel_launch(void* const* d_in, const int* in_sizes, int n_in,
                              void* d_out, int out_size, void* d_ws, size_t ws_size,
                              hipStream_t stream) {
  const float* x  = (const float*)d_in[0];
  const float* gw = (const float*)d_in[1];
  const float* w1 = (const float*)d_in[2];
  const float* w2 = (const float*)d_in[3];  // NOTE: dict order — w2 before w3
  const float* w3 = (const float*)d_in[4];
  float* out = (float*)d_out;

  uint8_t* ws = (uint8_t*)d_ws;
  size_t off = 0;
  auto alloc = [&](size_t bytes) -> void* {
    void* p = ws + off; off += (bytes + 255) & ~255ull; return p;
  };
  unsigned short* xb     = (unsigned short*)alloc((size_t)N_TOK * DIM * 2);
  unsigned short* w1b    = (unsigned short*)alloc((size_t)NEXP * HDIM * DIM * 2);
  unsigned short* w3b    = (unsigned short*)alloc((size_t)NEXP * HDIM * DIM * 2);
  unsigned short* w2b    = (unsigned short*)alloc((size_t)NEXP * DIM * HDIM * 2);
  unsigned short* hidden = (unsigned short*)alloc((size_t)NSLOT * HDIM * 2);
  int*   tok_e    = (int*)alloc(N_TOK * 2 * 4);
  float* tok_w    = (float*)alloc(N_TOK * 2 * 4);
  int*   slot_tok = (int*)alloc(NSLOT * 4);
  float* slot_w   = (float*)alloc(NSLOT * 4);
  int*   cnt_g    = (int*)alloc(NEXP * 4);
  int*   offs_g   = (int*)alloc(NEXP * 4);

  hipMemsetAsync(d_out, 0, (size_t)out_size * sizeof(float), stream);

  cvt_kernel<<<2048, 256, 0, stream>>>(x,  xb,  N_TOK * DIM / 4);
  cvt_kernel<<<2048, 256, 0, stream>>>(w1, w1b, NEXP * HDIM * DIM / 4);
  cvt_kernel<<<2048, 256, 0, stream>>>(w3, w3b, NEXP * HDIM * DIM / 4);
  cvt_kernel<<<2048, 256, 0, stream>>>(w2, w2b, NEXP * DIM * HDIM / 4);

  gate_kernel<<<N_TOK / 4, 256, 0, stream>>>(x, gw, tok_e, tok_w);
  route_kernel<<<1, 1024, 0, stream>>>(tok_e, tok_w, slot_tok, slot_w, cnt_g, offs_g);
  gemm1_kernel<<<NEXP * 16 * (HDIM / 128), 512, 0, stream>>>(
      xb, w1b, w3b, slot_tok, cnt_g, offs_g, hidden);
  gemm2_kernel<<<NEXP * 32 * (DIM / 128), 256, 0, stream>>>(
      hidden, w2b, slot_tok, slot_w, cnt_g, offs_g, out);
}

// Round 4
// 460.513 us; speedup vs baseline: 1.2158x; 1.0076x over previous
//
#include <hip/hip_runtime.h>
#include <stdint.h>

#define N_TOK 4096
#define DIM   1024
#define NEXP  8
#define HDIM  2048
#define NSLOT 8192   // N_TOK * K

typedef __attribute__((ext_vector_type(8))) short  short8;
typedef __attribute__((ext_vector_type(4))) float  f32x4;

__device__ inline unsigned short f2bf(float f) {
  union { float f; uint32_t u; } v; v.f = f;
  uint32_t u = v.u;
  u += 0x7fffu + ((u >> 16) & 1u);   // RNE (no NaN inputs here)
  return (unsigned short)(u >> 16);
}

// async global->LDS, 16B per lane; LDS dest is wave-uniform base + lane*16
__device__ inline void gload_lds16(const void* g, void* l) {
  __builtin_amdgcn_global_load_lds(
      (const __attribute__((address_space(1))) uint32_t*)g,
      (__attribute__((address_space(3))) uint32_t*)l, 16, 0, 0);
}

// ---------------- fused fp32 -> bf16 bulk convert (x, w1, w2, w3) ----------------
__global__ __launch_bounds__(256) void cvt_all_kernel(const float* __restrict__ x,
                                                      const float* __restrict__ w1,
                                                      const float* __restrict__ w2,
                                                      const float* __restrict__ w3,
                                                      unsigned short* __restrict__ xb,
                                                      unsigned short* __restrict__ w1b,
                                                      unsigned short* __restrict__ w2b,
                                                      unsigned short* __restrict__ w3b) {
  const int NX = N_TOK * DIM / 4;
  const int NW = NEXP * HDIM * DIM / 4;
  int i = blockIdx.x * blockDim.x + threadIdx.x;
  int stride = gridDim.x * blockDim.x;
  int total = NX + 3 * NW;
  for (; i < total; i += stride) {
    const float* s; unsigned short* d; int j;
    if (i < NX)               { s = x;  d = xb;  j = i; }
    else if (i < NX + NW)     { s = w1; d = w1b; j = i - NX; }
    else if (i < NX + 2 * NW) { s = w2; d = w2b; j = i - NX - NW; }
    else                      { s = w3; d = w3b; j = i - NX - 2 * NW; }
    float4 f = reinterpret_cast<const float4*>(s)[j];
    ushort4 o;
    o.x = f2bf(f.x); o.y = f2bf(f.y); o.z = f2bf(f.z); o.w = f2bf(f.w);
    reinterpret_cast<ushort4*>(d)[j] = o;
  }
}

// ---------------- gating: logits, softmax, top-2 ----------------
__global__ __launch_bounds__(256) void gate_kernel(const float* __restrict__ x,
                                                   const float* __restrict__ gw,
                                                   int* __restrict__ tok_e,
                                                   float* __restrict__ tok_w) {
  __shared__ float gws[NEXP * DIM];   // 32 KB
  int tid = threadIdx.x;
  for (int i = tid; i < NEXP * DIM; i += 256) gws[i] = gw[i];
  __syncthreads();
  int lane = tid & 63;
  int token = blockIdx.x * 4 + (tid >> 6);
  const float* xr = x + (size_t)token * DIM;
  float acc[NEXP];
#pragma unroll
  for (int e = 0; e < NEXP; ++e) acc[e] = 0.f;
  for (int i = 0; i < DIM / 64; ++i) {
    float xv = xr[i * 64 + lane];
#pragma unroll
    for (int e = 0; e < NEXP; ++e) acc[e] += xv * gws[e * DIM + i * 64 + lane];
  }
#pragma unroll
  for (int off = 32; off > 0; off >>= 1) {
#pragma unroll
    for (int e = 0; e < NEXP; ++e) acc[e] += __shfl_xor(acc[e], off);
  }
  if (lane == 0) {
    float m = acc[0];
#pragma unroll
    for (int e = 1; e < NEXP; ++e) m = fmaxf(m, acc[e]);
    float ex[NEXP], Z = 0.f;
#pragma unroll
    for (int e = 0; e < NEXP; ++e) { ex[e] = expf(acc[e] - m); Z += ex[e]; }
    int b0 = 0; float v0 = ex[0];
#pragma unroll
    for (int e = 1; e < NEXP; ++e) if (ex[e] > v0) { v0 = ex[e]; b0 = e; }  // first on tie
    int b1 = -1; float v1 = -1.f;
#pragma unroll
    for (int e = 0; e < NEXP; ++e) if (e != b0 && ex[e] > v1) { v1 = ex[e]; b1 = e; }
    float p0 = v0 / Z, p1 = v1 / Z;
    float s = p0 + p1 + 1e-8f;
    tok_e[token * 2 + 0] = b0; tok_e[token * 2 + 1] = b1;
    tok_w[token * 2 + 0] = p0 / s; tok_w[token * 2 + 1] = p1 / s;
  }
}

// ---------------- compaction: expert slot lists ----------------
__global__ __launch_bounds__(1024) void route_kernel(const int* __restrict__ tok_e,
                                                     const float* __restrict__ tok_w,
                                                     int* __restrict__ slot_tok,
                                                     float* __restrict__ slot_w,
                                                     int* __restrict__ cnt_g,
                                                     int* __restrict__ offs_g) {
  __shared__ int cnt[NEXP], offs[NEXP], cur[NEXP];
  int tid = threadIdx.x;
  if (tid < NEXP) cnt[tid] = 0;
  __syncthreads();
  for (int n = tid; n < N_TOK; n += 1024) {
    atomicAdd(&cnt[tok_e[2 * n]], 1);
    atomicAdd(&cnt[tok_e[2 * n + 1]], 1);
  }
  __syncthreads();
  if (tid == 0) {
    int o = 0;
    for (int e = 0; e < NEXP; ++e) { offs[e] = o; cur[e] = o; o += cnt[e]; }
    for (int e = 0; e < NEXP; ++e) { cnt_g[e] = cnt[e]; offs_g[e] = offs[e]; }
  }
  __syncthreads();
  for (int n = tid; n < N_TOK; n += 1024) {
#pragma unroll
    for (int k = 0; k < 2; ++k) {
      int e = tok_e[2 * n + k];
      int p = atomicAdd(&cur[e], 1);
      slot_tok[p] = n;
      slot_w[p] = tok_w[2 * n + k];
    }
  }
}

// ---------------- GEMM1: h=x@w1^T, g=x@w3^T, hidden=silu(h)*g ----------------
// 256x128 tile, BK=64, 8 waves (4Mx2N, wave 64x64 dual-acc).
// 4-phase K-loop, half-tile stage stream, counted vmcnt (T4), setprio (T5).
__global__ __launch_bounds__(512, 2) void gemm1_kernel(const unsigned short* __restrict__ xb,
                                                       const unsigned short* __restrict__ w1b,
                                                       const unsigned short* __restrict__ w3b,
                                                       const int* __restrict__ slot_tok,
                                                       const int* __restrict__ cnt_g,
                                                       const int* __restrict__ offs_g,
                                                       unsigned short* __restrict__ hidden) {
  const int ROWT = 16;            // max 4096/256 row-tiles per expert
  const int COLT = HDIM / 128;    // 16
  int bid = blockIdx.x;
  int e  = bid / (ROWT * COLT);
  int rt = (bid / COLT) % ROWT;
  int ct = bid % COLT;
  int cnt = cnt_g[e];
  if (rt * 256 >= cnt) return;
  int rowBase = offs_g[e] + rt * 256;

  __shared__ alignas(16) unsigned short As[2][256 * 64];   // 64 KB
  __shared__ alignas(16) unsigned short B1s[2][128 * 64];  // 32 KB
  __shared__ alignas(16) unsigned short B3s[2][128 * 64];  // 32 KB
  __shared__ int toks[256];

  int tid = threadIdx.x;
  if (tid < 256) {
    int slot = rowBase + tid; if (slot > NSLOT - 1) slot = NSLOT - 1;
    toks[tid] = slot_tok[slot];
  }
  __syncthreads();

  int wave = tid >> 6, lane = tid & 63;
  int wr = (wave >> 1) * 64;      // 0..192 (4 M-waves)
  int wc = (wave & 1) * 64;       // 0 or 64 (2 N-waves)
  int sub = lane >> 3;            // row within 8-row chunk
  int swcol = (((lane & 7) ^ sub) << 3);  // swizzled source column (elements)

  // hoisted per-lane stage pointers (K-invariant part)
  const size_t wbase = (size_t)e * HDIM * DIM;
  const unsigned short* aptr[4];
  const unsigned short* b1ptr[2];
  const unsigned short* b3ptr[2];
#pragma unroll
  for (int i = 0; i < 4; ++i) {
    int r = (wave + i * 8) * 8 + sub;          // 0..255
    aptr[i] = xb + (size_t)toks[r] * DIM + swcol;
  }
#pragma unroll
  for (int i = 0; i < 2; ++i) {
    int r = (wave + i * 8) * 8 + sub;          // 0..127
    b1ptr[i] = w1b + wbase + (size_t)(ct * 128 + r) * DIM + swcol;
    b3ptr[i] = w3b + wbase + (size_t)(ct * 128 + r) * DIM + swcol;
  }

  f32x4 hacc[4][4], gacc[4][4];
#pragma unroll
  for (int m = 0; m < 4; ++m)
#pragma unroll
    for (int n = 0; n < 4; ++n) {
      hacc[m][n] = (f32x4){0.f, 0.f, 0.f, 0.f};
      gacc[m][n] = (f32x4){0.f, 0.f, 0.f, 0.f};
    }

  // prologue: stage all 4 halves of tile 0 (FIFO order h0,h1,h2,h3)
  gload_lds16(aptr[0], &As[0][(wave + 0) * 512]);
  gload_lds16(aptr[1], &As[0][(wave + 8) * 512]);
  gload_lds16(aptr[2], &As[0][(wave + 16) * 512]);
  gload_lds16(aptr[3], &As[0][(wave + 24) * 512]);
  gload_lds16(b1ptr[0], &B1s[0][wave * 512]);
  gload_lds16(b1ptr[1], &B1s[0][(wave + 8) * 512]);
  gload_lds16(b3ptr[0], &B3s[0][wave * 512]);
  gload_lds16(b3ptr[1], &B3s[0][(wave + 8) * 512]);

  const int NKT = DIM / 64;   // 16
  int key = (lane & 7) << 3;
  int l15 = lane & 15;
  int pc0 = ((lane >> 4) * 8) ^ key;
  int pc1 = (32 + (lane >> 4) * 8) ^ key;

  for (int kt = 0; kt < NKT; ++kt) {
    int c = kt & 1;
    int nk = (kt + 1) * 64;
    bool pre = (kt + 1 < NKT);

    __builtin_amdgcn_sched_barrier(0);
    __builtin_amdgcn_s_barrier();            // barrier1: buf c^1 free for staging
    __builtin_amdgcn_sched_barrier(0);
    if (pre) {
      // stage h0(t+1): A rows 0-127
      gload_lds16(aptr[0] + nk, &As[c ^ 1][(wave + 0) * 512]);
      gload_lds16(aptr[1] + nk, &As[c ^ 1][(wave + 8) * 512]);
      asm volatile("s_waitcnt vmcnt(4)" ::: "memory");  // h0,h1,h2(t) done
    } else {
      asm volatile("s_waitcnt vmcnt(2)" ::: "memory");  // h0,h1,h2(t) done (tail)
    }
    __builtin_amdgcn_sched_barrier(0);
    __builtin_amdgcn_s_barrier();            // barrier2: A + B1 of tile t visible
    __builtin_amdgcn_sched_barrier(0);

    short8 a0[4], a1[4], bv[4];
    // ---- phase 0: ks0 x B1 -> hacc ----
#pragma unroll
    for (int m = 0; m < 4; ++m)
      a0[m] = *(const short8*)&As[c][(wr + m * 16 + l15) * 64 + pc0];
#pragma unroll
    for (int n = 0; n < 4; ++n)
      bv[n] = *(const short8*)&B1s[c][(wc + n * 16 + l15) * 64 + pc0];
    if (pre) {            // stage h1(t+1): A rows 128-255
      gload_lds16(aptr[2] + nk, &As[c ^ 1][(wave + 16) * 512]);
      gload_lds16(aptr[3] + nk, &As[c ^ 1][(wave + 24) * 512]);
    }
    __builtin_amdgcn_s_setprio(1);
#pragma unroll
    for (int m = 0; m < 4; ++m)
#pragma unroll
      for (int n = 0; n < 4; ++n)
        hacc[m][n] = __builtin_amdgcn_mfma_f32_16x16x32_bf16(a0[m], bv[n], hacc[m][n], 0, 0, 0);
    __builtin_amdgcn_s_setprio(0);

    // ---- phase 1: ks1 x B1 -> hacc ----
#pragma unroll
    for (int m = 0; m < 4; ++m)
      a1[m] = *(const short8*)&As[c][(wr + m * 16 + l15) * 64 + pc1];
#pragma unroll
    for (int n = 0; n < 4; ++n)
      bv[n] = *(const short8*)&B1s[c][(wc + n * 16 + l15) * 64 + pc1];
    if (pre) {            // stage h2(t+1): B1
      gload_lds16(b1ptr[0] + nk, &B1s[c ^ 1][wave * 512]);
      gload_lds16(b1ptr[1] + nk, &B1s[c ^ 1][(wave + 8) * 512]);
    }
    __builtin_amdgcn_s_setprio(1);
#pragma unroll
    for (int m = 0; m < 4; ++m)
#pragma unroll
      for (int n = 0; n < 4; ++n)
        hacc[m][n] = __builtin_amdgcn_mfma_f32_16x16x32_bf16(a1[m], bv[n], hacc[m][n], 0, 0, 0);
    __builtin_amdgcn_s_setprio(0);

    // ---- mid wait: B3(t) staged by all waves ----
    if (pre) asm volatile("s_waitcnt vmcnt(6)" ::: "memory");  // h3(t) done
    else     asm volatile("s_waitcnt vmcnt(0)" ::: "memory");
    __builtin_amdgcn_sched_barrier(0);
    __builtin_amdgcn_s_barrier();            // barrier3: B3 of tile t visible
    __builtin_amdgcn_sched_barrier(0);

    // ---- phase 2: ks0 x B3 -> gacc ----
#pragma unroll
    for (int n = 0; n < 4; ++n)
      bv[n] = *(const short8*)&B3s[c][(wc + n * 16 + l15) * 64 + pc0];
    if (pre) {            // stage h3(t+1): B3
      gload_lds16(b3ptr[0] + nk, &B3s[c ^ 1][wave * 512]);
      gload_lds16(b3ptr[1] + nk, &B3s[c ^ 1][(wave + 8) * 512]);
    }
    __builtin_amdgcn_s_setprio(1);
#pragma unroll
    for (int m = 0; m < 4; ++m)
#pragma unroll
      for (int n = 0; n < 4; ++n)
        gacc[m][n] = __builtin_amdgcn_mfma_f32_16x16x32_bf16(a0[m], bv[n], gacc[m][n], 0, 0, 0);
    __builtin_amdgcn_s_setprio(0);

    // ---- phase 3: ks1 x B3 -> gacc ----
#pragma unroll
    for (int n = 0; n < 4; ++n)
      bv[n] = *(const short8*)&B3s[c][(wc + n * 16 + l15) * 64 + pc1];
    __builtin_amdgcn_s_setprio(1);
#pragma unroll
    for (int m = 0; m < 4; ++m)
#pragma unroll
      for (int n = 0; n < 4; ++n)
        gacc[m][n] = __builtin_amdgcn_mfma_f32_16x16x32_bf16(a1[m], bv[n], gacc[m][n], 0, 0, 0);
    __builtin_amdgcn_s_setprio(0);
  }

  int cbase = ct * 128 + wc;
#pragma unroll
  for (int m = 0; m < 4; ++m) {
#pragma unroll
    for (int q = 0; q < 4; ++q) {
      int r = wr + m * 16 + ((lane >> 4) * 4 + q);
      if (rt * 256 + r < cnt) {
        size_t rowoff = (size_t)(rowBase + r) * HDIM + cbase;
#pragma unroll
        for (int n = 0; n < 4; ++n) {
          float h = hacc[m][n][q], g = gacc[m][n][q];
          float val = (h / (1.f + expf(-h))) * g;   // silu(h)*g
          hidden[rowoff + n * 16 + (lane & 15)] = f2bf(val);
        }
      }
    }
  }
}

// ---------------- GEMM2: eo = act @ w2^T, weighted atomic into out ----------------
// 128x128 tile, BK=64, 4 waves (2x2), 2-phase K-loop, counted vmcnt, setprio.
__global__ __launch_bounds__(256, 2) void gemm2_kernel(const unsigned short* __restrict__ hidden,
                                                       const unsigned short* __restrict__ w2b,
                                                       const int* __restrict__ slot_tok,
                                                       const float* __restrict__ slot_w,
                                                       const int* __restrict__ cnt_g,
                                                       const int* __restrict__ offs_g,
                                                       float* __restrict__ out) {
  const int ROWT = 32;            // max 4096/128 row-tiles per expert
  const int COLT = DIM / 128;     // 8
  int bid = blockIdx.x;
  int e  = bid / (ROWT * COLT);
  int rt = (bid / COLT) % ROWT;
  int ct = bid % COLT;
  int cnt = cnt_g[e];
  if (rt * 128 >= cnt) return;
  int rowBase = offs_g[e] + rt * 128;

  __shared__ alignas(16) unsigned short As[2][128 * 64];   // 32 KB
  __shared__ alignas(16) unsigned short Bs[2][128 * 64];   // 32 KB
  __shared__ int   toks[128];
  __shared__ float wgt[128];

  int tid = threadIdx.x;
  if (tid < 128) {
    int slot = rowBase + tid; if (slot > NSLOT - 1) slot = NSLOT - 1;
    toks[tid] = slot_tok[slot];
    wgt[tid]  = slot_w[slot];
  }
  __syncthreads();

  int wave = tid >> 6, lane = tid & 63;
  int wr = (wave >> 1) * 64, wc = (wave & 1) * 64;
  int sub = lane >> 3;
  int swcol = (((lane & 7) ^ sub) << 3);

  const size_t w2base = (size_t)e * DIM * HDIM;
  const unsigned short* aptr[4];
  const unsigned short* bptr[4];
#pragma unroll
  for (int i = 0; i < 4; ++i) {
    int r = (wave + i * 4) * 8 + sub;            // 0..127
    int rg = rowBase + r; if (rg > NSLOT - 1) rg = NSLOT - 1;
    aptr[i] = hidden + (size_t)rg * HDIM + swcol;
    bptr[i] = w2b + w2base + (size_t)(ct * 128 + r) * HDIM + swcol;
  }

  f32x4 acc[4][4];
#pragma unroll
  for (int m = 0; m < 4; ++m)
#pragma unroll
    for (int n = 0; n < 4; ++n) acc[m][n] = (f32x4){0.f, 0.f, 0.f, 0.f};

  // prologue: stage tile 0 (A then B, FIFO)
#pragma unroll
  for (int i = 0; i < 4; ++i)
    gload_lds16(aptr[i], &As[0][(wave + i * 4) * 512]);
#pragma unroll
  for (int i = 0; i < 4; ++i)
    gload_lds16(bptr[i], &Bs[0][(wave + i * 4) * 512]);

  const int NKT = HDIM / 64;   // 32
  int key = (lane & 7) << 3;
  int l15 = lane & 15;
  int pc0 = ((lane >> 4) * 8) ^ key;
  int pc1 = (32 + (lane >> 4) * 8) ^ key;

  for (int kt = 0; kt < NKT; ++kt) {
    int c = kt & 1;
    int nk = (kt + 1) * 64;
    bool pre = (kt + 1 < NKT);

    __builtin_amdgcn_sched_barrier(0);
    __builtin_amdgcn_s_barrier();            // buf c^1 free
    __builtin_amdgcn_sched_barrier(0);
    if (pre) {
      // stage A(t+1)
#pragma unroll
      for (int i = 0; i < 4; ++i)
        gload_lds16(aptr[i] + nk, &As[c ^ 1][(wave + i * 4) * 512]);
      asm volatile("s_waitcnt vmcnt(4)" ::: "memory");  // A(t)+B(t) done
    } else {
      asm volatile("s_waitcnt vmcnt(0)" ::: "memory");
    }
    __builtin_amdgcn_sched_barrier(0);
    __builtin_amdgcn_s_barrier();            // tile t visible
    __builtin_amdgcn_sched_barrier(0);

    short8 a[4], b[4];
    // ---- phase 0: ks0 ----
#pragma unroll
    for (int m = 0; m < 4; ++m)
      a[m] = *(const short8*)&As[c][(wr + m * 16 + l15) * 64 + pc0];
#pragma unroll
    for (int n = 0; n < 4; ++n)
      b[n] = *(const short8*)&Bs[c][(wc + n * 16 + l15) * 64 + pc0];
    if (pre) {
#pragma unroll
      for (int i = 0; i < 4; ++i)
        gload_lds16(bptr[i] + nk, &Bs[c ^ 1][(wave + i * 4) * 512]);
    }
    __builtin_amdgcn_s_setprio(1);
#pragma unroll
    for (int m = 0; m < 4; ++m)
#pragma unroll
      for (int n = 0; n < 4; ++n)
        acc[m][n] = __builtin_amdgcn_mfma_f32_16x16x32_bf16(a[m], b[n], acc[m][n], 0, 0, 0);
    __builtin_amdgcn_s_setprio(0);

    // ---- phase 1: ks1 ----
#pragma unroll
    for (int m = 0; m < 4; ++m)
      a[m] = *(const short8*)&As[c][(wr + m * 16 + l15) * 64 + pc1];
#pragma unroll
    for (int n = 0; n < 4; ++n)
      b[n] = *(const short8*)&Bs[c][(wc + n * 16 + l15) * 64 + pc1];
    __builtin_amdgcn_s_setprio(1);
#pragma unroll
    for (int m = 0; m < 4; ++m)
#pragma unroll
      for (int n = 0; n < 4; ++n)
        acc[m][n] = __builtin_amdgcn_mfma_f32_16x16x32_bf16(a[m], b[n], acc[m][n], 0, 0, 0);
    __builtin_amdgcn_s_setprio(0);
  }

  int cbase = ct * 128 + wc;
#pragma unroll
  for (int m = 0; m < 4; ++m) {
#pragma unroll
    for (int q = 0; q < 4; ++q) {
      int r = wr + m * 16 + ((lane >> 4) * 4 + q);
      if (rt * 128 + r < cnt) {
        float w = wgt[r];
        float* orow = out + (size_t)toks[r] * DIM + cbase;
#pragma unroll
        for (int n = 0; n < 4; ++n)
          unsafeAtomicAdd(&orow[n * 16 + (lane & 15)], acc[m][n][q] * w);
      }
    }
  }
}

extern "C" void kernel_launch(void* const* d_in, const int* in_sizes, int n_in,
                              void* d_out, int out_size, void* d_ws, size_t ws_size,
                              hipStream_t stream) {
  const float* x  = (const float*)d_in[0];
  const float* gw = (const float*)d_in[1];
  const float* w1 = (const float*)d_in[2];
  const float* w2 = (const float*)d_in[3];  // NOTE: dict order — w2 before w3
  const float* w3 = (const float*)d_in[4];
  float* out = (float*)d_out;

  uint8_t* ws = (uint8_t*)d_ws;
  size_t off = 0;
  auto alloc = [&](size_t bytes) -> void* {
    void* p = ws + off; off += (bytes + 255) & ~255ull; return p;
  };
  unsigned short* xb     = (unsigned short*)alloc((size_t)N_TOK * DIM * 2);
  unsigned short* w1b    = (unsigned short*)alloc((size_t)NEXP * HDIM * DIM * 2);
  unsigned short* w3b    = (unsigned short*)alloc((size_t)NEXP * HDIM * DIM * 2);
  unsigned short* w2b    = (unsigned short*)alloc((size_t)NEXP * DIM * HDIM * 2);
  unsigned short* hidden = (unsigned short*)alloc((size_t)NSLOT * HDIM * 2);
  int*   tok_e    = (int*)alloc(N_TOK * 2 * 4);
  float* tok_w    = (float*)alloc(N_TOK * 2 * 4);
  int*   slot_tok = (int*)alloc(NSLOT * 4);
  float* slot_w   = (float*)alloc(NSLOT * 4);
  int*   cnt_g    = (int*)alloc(NEXP * 4);
  int*   offs_g   = (int*)alloc(NEXP * 4);

  hipMemsetAsync(d_out, 0, (size_t)out_size * sizeof(float), stream);

  cvt_all_kernel<<<2048, 256, 0, stream>>>(x, w1, w2, w3, xb, w1b, w2b, w3b);

  gate_kernel<<<N_TOK / 4, 256, 0, stream>>>(x, gw, tok_e, tok_w);
  route_kernel<<<1, 1024, 0, stream>>>(tok_e, tok_w, slot_tok, slot_w, cnt_g, offs_g);
  gemm1_kernel<<<NEXP * 16 * (HDIM / 128), 512, 0, stream>>>(
      xb, w1b, w3b, slot_tok, cnt_g, offs_g, hidden);
  gemm2_kernel<<<NEXP * 32 * (DIM / 128), 256, 0, stream>>>(
      hidden, w2b, slot_tok, slot_w, cnt_g, offs_g, out);
}